// Round 5
// baseline (73.741 us; speedup 1.0000x reference)
//
#include <hip/hip_runtime.h>
#include <math.h>

// S4D diagonal SSM kernel generation (ZOH, real_type='exp', rep=1)
// K[h,l] = sum_n Re( G[h,n] * w[h,n]^l ),  w = exp(dt*A),  G = 2*B*C*(w-1)/A.
//
// Round-5: latency-exposure fixes (R4 showed instruction count was not the
// limiter; LDS + transcendental latency at 3 waves/SIMD was):
//  - init in 2 phases of 8 n (was 4 phases of 4): 8 independent
//    fract/sincos/exp2 chains + 16 b128 LDS loads issued together.
//  - sP1 packs {Gwr, Gwi, 2Re(w), -|w|^2}: one b128/n, no wasted bytes.
//  - single-stage v2f reduction, 2 barriers total (was 4): nb 1..3 write
//    packed partials (b64 stride-1, conflict-free), nb 0 adds and stores.
//  - inner loop: 4 independent pair-packed order-2 recurrence chains
//    r_{l+1} = 2Re(w) r_l - |w|^2 r_{l-1} (v_pk_mul/fma/add),
//    1.5 issues per (n,l) — at the formulation floor.
//  - block 256 (4 waves), grid 768 = 256 CU x 3 resident, zero tail.

typedef float v2f __attribute__((ext_vector_type(2)));

#define H_DIM 768
#define N_DIM 64
#define L_DIM 2048
#define TPB   256
#define LTH   64   // l-threads per h
#define LCH   32   // l per thread

__global__ __launch_bounds__(TPB, 3) void s4d_gen_kernel(
    const float* __restrict__ log_dt,
    const float* __restrict__ B_ri,
    const float* __restrict__ inv_A_real,
    const float* __restrict__ A_imag,
    const float* __restrict__ C_ri,
    float* __restrict__ out)
{
    __shared__ float4 sP0[N_DIM];           // {revs(w^32) mod 1, log2|w^32|, Gr, Gi}
    __shared__ float4 sP1[N_DIM];           // {Gwr, Gwi, 2Re(w), -|w|^2}
    __shared__ v2f    sRedV[3][LCH][LTH];   // packed partials, [grp-1][j][tl]

    const int h  = blockIdx.x;
    const int t  = threadIdx.x;
    const int nb = t >> 6;   // n-group 0..3 (wave-uniform)
    const int tl = t & 63;   // l-chunk  0..63

    // ---- setup: one thread per n ----
    if (t < N_DIM) {
        const int n   = t;
        const int idx = h * N_DIM + n;
        const float dt = expf(log_dt[h]);
        const float Ar = -expf(inv_A_real[idx]);
        const float Ai = A_imag[idx];
        const float dtAr = Ar * dt;
        const float dtAi = Ai * dt;
        const float e  = expf(dtAr);
        float s, c;
        sincosf(dtAi, &s, &c);
        const float wr = e * c, wi = e * s;
        const float inv = 1.0f / (Ar * Ar + Ai * Ai);
        const float nr = wr - 1.0f, ni = wi;
        const float qr = (nr * Ar + ni * Ai) * inv;
        const float qi = (ni * Ar - nr * Ai) * inv;
        const float Br = B_ri[2 * idx], Bi = B_ri[2 * idx + 1];
        const float Cr = C_ri[2 * idx], Ci = C_ri[2 * idx + 1];
        const float BCr = Br * Cr - Bi * Ci;
        const float BCi = Br * Ci + Bi * Cr;
        const float Gr = 2.0f * (BCr * qr - BCi * qi);
        const float Gi = 2.0f * (BCr * qi + BCi * qr);
        // phase of w^32 in revolutions, reduced mod 1 in double (setup-only)
        const double revs32 = (double)dtAi * (32.0 / (2.0 * M_PI));
        const float  r32f   = (float)(revs32 - floor(revs32));
        const float  l2m32  = dtAr * (32.0f * 1.4426950408889634f);
        sP0[n] = make_float4(r32f, l2m32, Gr, Gi);
        sP1[n] = make_float4(Gr * wr - Gi * wi, Gr * wi + Gi * wr,
                             2.0f * wr, -(wr * wr + wi * wi));
    }
    __syncthreads();

    v2f acc2[LCH];
    #pragma unroll
    for (int j = 0; j < LCH; ++j) acc2[j] = (v2f){0.0f, 0.0f};

    const int   nbase = nb * 16;
    const float tlf   = (float)tl;

    #pragma unroll
    for (int half = 0; half < 2; ++half) {
        const int n0 = nbase + half * 8;

        // ---- init: 8 n at once, polar u = w^(32 tl); seeds s0=Re(Gu), s1=Re(Gwu)
        float s0s[8], s1s[8], c1s[8], nc2s[8];
        #pragma unroll
        for (int k = 0; k < 8; ++k) {
            const float4 p = sP0[n0 + k];
            const float4 q = sP1[n0 + k];
            const float f  = __builtin_amdgcn_fractf(p.x * tlf);
            const float m  = __builtin_amdgcn_exp2f(p.y * tlf);
            const float cs = __builtin_amdgcn_cosf(f);
            const float sn = __builtin_amdgcn_sinf(f);
            const float ur = m * cs, ui = m * sn;
            s0s[k]  = fmaf(p.z, ur, -(p.w * ui));
            s1s[k]  = fmaf(q.x, ur, -(q.y * ui));
            c1s[k]  = q.z;
            nc2s[k] = q.w;
        }
        v2f S0[4], S1[4], C1[4], NC2[4];
        #pragma unroll
        for (int k = 0; k < 4; ++k) {
            S0[k]  = (v2f){s0s[2*k],  s0s[2*k+1]};
            S1[k]  = (v2f){s1s[2*k],  s1s[2*k+1]};
            C1[k]  = (v2f){c1s[2*k],  c1s[2*k+1]};
            NC2[k] = (v2f){nc2s[2*k], nc2s[2*k+1]};
        }

        // ---- inner: 4 independent pair-packed order-2 recurrence chains ----
        #pragma unroll
        for (int j = 0; j < LCH; ++j) {
            const v2f t1 = S0[0] + S0[1];
            const v2f t2 = S0[2] + S0[3];
            acc2[j] += t1;
            acc2[j] += t2;
            #pragma unroll
            for (int k = 0; k < 4; ++k) {
                v2f tt = C1[k] * S1[k];                                // v_pk_mul_f32
                v2f nn = __builtin_elementwise_fma(NC2[k], S0[k], tt); // v_pk_fma_f32
                S0[k] = S1[k]; S1[k] = nn;
            }
        }
    }

    // ---- single-stage packed reduction over the 4 n-groups ----
    if (nb != 0) {
        #pragma unroll
        for (int j = 0; j < LCH; ++j) sRedV[nb - 1][j][tl] = acc2[j];
    }
    __syncthreads();
    if (nb == 0) {
        #pragma unroll
        for (int j = 0; j < LCH; ++j) {
            const v2f a = sRedV[0][j][tl];
            const v2f b = sRedV[1][j][tl];
            const v2f c = sRedV[2][j][tl];
            acc2[j] += a + b + c;
        }
        float acc[LCH];
        #pragma unroll
        for (int j = 0; j < LCH; ++j) acc[j] = acc2[j].x + acc2[j].y;
        float* op = out + (size_t)h * L_DIM + tl * LCH;
        #pragma unroll
        for (int j = 0; j < LCH; j += 4) {
            *reinterpret_cast<float4*>(op + j) =
                make_float4(acc[j], acc[j + 1], acc[j + 2], acc[j + 3]);
        }
    }
}

extern "C" void kernel_launch(void* const* d_in, const int* in_sizes, int n_in,
                              void* d_out, int out_size, void* d_ws, size_t ws_size,
                              hipStream_t stream) {
    const float* log_dt     = (const float*)d_in[0];
    const float* B_ri       = (const float*)d_in[1];
    const float* inv_A_real = (const float*)d_in[2];
    const float* A_imag     = (const float*)d_in[3];
    const float* C_ri       = (const float*)d_in[4];
    float* out = (float*)d_out;
    hipLaunchKernelGGL(s4d_gen_kernel, dim3(H_DIM), dim3(TPB), 0, stream,
                       log_dt, B_ri, inv_A_real, A_imag, C_ri, out);
}